// Round 5
// baseline (168.226 us; speedup 1.0000x reference)
//
#include <hip/hip_runtime.h>
#include <stdint.h>

// S=512, B=64, H=8, K=12, P=9, L=137, T=4096, THRESH=4
// Workspace layout (u32 units):
//   WS_TOK [0, 1024)      packed token rows: 512 u64 = 4 KB
//   WS_PAR [1024, 9216)   parity bits: [hb][chunk(8)][2] u32 = 32 KB
#define WS_TOK 0
#define WS_PAR 1024

// ---- Kernel A: pack token rows into u64 bitmasks (32 blocks) ----
__global__ __launch_bounds__(256) void softram_tok_kernel(
    const int* __restrict__ tokens,   // (512, 64)
    uint32_t* __restrict__ ws)
{
    const int tid = threadIdx.x, lane = tid & 63, w = tid >> 6;
    unsigned long long* tokp = (unsigned long long*)(ws + WS_TOK);
    const int c0 = blockIdx.x * 4;
    #pragma unroll
    for (int g = 0; g < 4; ++g) {
        int c = c0 + g;                          // s = c*4 + w, bit = lane (=b)
        int v = tokens[c * 256 + tid];
        unsigned long long m = __ballot(v != 0);
        if (lane == 0) tokp[c * 4 + w] = m;
    }
}

// ---- inner chunk loop, templated on r-bit count; MUST stay fully inlined ----
template<int NR>
__device__ __forceinline__ uint32_t do_chunk(
    int c, int w, int lane, int aq, int p0, int m0, int p1, int m1,
    const unsigned short* AkL, const unsigned short* ArL, const uint8_t* tbl)
{
    uint32_t acc = 0;
    for (int sb = w; sb < c; sb += 4) {          // full sub-blocks, d >= 1
        int akv = (int)AkL[sb * 64 + lane];
        int dbase = (c - sb) * 64 + lane;
        #pragma unroll
        for (int jj = 0; jj < 64; ++jj) {
            int sak = __builtin_amdgcn_readlane(akv, jj);  // wave-uniform Ak[j]
            int addr = aq + sak;
            if (NR == 1) {
                int d = dbase - jj;
                addr += (0 - ((d >> p0) & 1)) & m0;
            } else if (NR == 2) {
                int d = dbase - jj;
                addr += (0 - ((d >> p0) & 1)) & m0;
                addr += (0 - ((d >> p1) & 1)) & m1;
            } else if (NR >= 3) {
                int d = dbase - jj;
                addr += (int)ArL[d];
            }
            acc ^= tbl[addr];                    // ds_read_u8, value in {0,1}
        }
    }
    if (w == (c & 3)) {                          // tail sub-block sb == c
        int akv = (int)AkL[c * 64 + lane];
        #pragma unroll
        for (int jj = 0; jj < 64; ++jj) {
            int sak = __builtin_amdgcn_readlane(akv, jj);
            int d = lane - jj;                   // may be < 0
            int dm = d & ~(d >> 31);             // max(d, 0)
            int addr = aq + sak;
            if (NR == 1) {
                addr += (0 - ((dm >> p0) & 1)) & m0;
            } else if (NR == 2) {
                addr += (0 - ((dm >> p0) & 1)) & m0;
                addr += (0 - ((dm >> p1) & 1)) & m1;
            } else if (NR >= 3) {
                addr += (int)ArL[dm];
            }
            uint32_t keep = (uint32_t)(~(d >> 31));   // 0 if d < 0
            acc ^= tbl[addr] & keep;
        }
    }
    return acc;
}

// ---- Kernel B: parity. 4 blocks per hb (block q owns chunks {q, 7-q});
//      sub-blocks split mod 4 across the 4 waves. ----
__global__ __launch_bounds__(256) void softram_parity_kernel(
    const int* __restrict__ conn,     // (8, 64, 12)
    const float* __restrict__ ram,    // (8, 64, 4096) values in {0,1}
    uint32_t* __restrict__ ws)
{
    __shared__ uint8_t tbl[4096];                // byte-expanded RAM table
    __shared__ unsigned short AqL[512], AkL[512], ArL[512];
    __shared__ unsigned long long parbuf[2][4];

    const int tid  = threadIdx.x;
    const int lane = tid & 63;
    const int w    = tid >> 6;
    const int hb   = blockIdx.x >> 2;
    const int q    = blockIdx.x & 3;

    // stage byte table straight from ram (16 KB coalesced, L2-resident)
    {
        const float4* rp4 = (const float4*)(ram + (size_t)hb * 4096);
        uint32_t* tbl32 = (uint32_t*)tbl;
        #pragma unroll
        for (int c = 0; c < 4; ++c) {
            float4 f = rp4[c * 256 + tid];
            uint32_t b = (f.x > 0.5f ? 1u : 0u)
                       | (f.y > 0.5f ? 0x100u : 0u)
                       | (f.z > 0.5f ? 0x10000u : 0u)
                       | (f.w > 0.5f ? 0x1000000u : 0u);
            tbl32[c * 256 + tid] = b;
        }
    }

    // wave-uniform conn info
    const int* cp = conn + hb * 12;
    int ck[12];
    #pragma unroll
    for (int k = 0; k < 12; ++k) ck[k] = cp[k];
    int p0 = 0, m0 = 0, p1 = 0, m1 = 0, nr = 0;
    #pragma unroll
    for (int k = 0; k < 12; ++k) {
        int cv = ck[k];
        if (cv >= 128) {
            if (nr == 0)      { p0 = cv - 128; m0 = 1 << k; }
            else if (nr == 1) { p1 = cv - 128; m1 = 1 << k; }
            ++nr;
        }
    }

    // per-position partial addresses from packed token rows
    const unsigned long long* tokp = (const unsigned long long*)(ws + WS_TOK);
    #pragma unroll
    for (int rep = 0; rep < 2; ++rep) {
        int s = tid + rep * 256;
        unsigned long long row = tokp[s];
        int aq = 0, ak = 0, ar = 0;
        #pragma unroll
        for (int k = 0; k < 12; ++k) {
            int cv = ck[k];                      // wave-uniform branch
            if (cv < 64)       aq |= (int)((row >> cv) & 1ull) << k;
            else if (cv < 128) ak |= (int)((row >> (cv - 64)) & 1ull) << k;
            else               ar += ((s >> (cv - 128)) & 1) << k;
        }
        AqL[s] = (unsigned short)aq;
        AkL[s] = (unsigned short)ak;
        ArL[s] = (unsigned short)ar;
    }
    __syncthreads();

    const int chunks[2] = { q, 7 - q };
    uint32_t accs[2];

    #pragma unroll 1
    for (int ci = 0; ci < 2; ++ci) {
        const int c  = chunks[ci];
        const int aq = (int)AqL[c * 64 + lane];
        uint32_t a;
        if      (nr == 0) a = do_chunk<0>(c, w, lane, aq, p0, m0, p1, m1, AkL, ArL, tbl);
        else if (nr == 1) a = do_chunk<1>(c, w, lane, aq, p0, m0, p1, m1, AkL, ArL, tbl);
        else if (nr == 2) a = do_chunk<2>(c, w, lane, aq, p0, m0, p1, m1, AkL, ArL, tbl);
        else              a = do_chunk<3>(c, w, lane, aq, p0, m0, p1, m1, AkL, ArL, tbl);
        accs[ci] = a & 1u;
    }

    #pragma unroll
    for (int ci = 0; ci < 2; ++ci) {
        unsigned long long m = __ballot(accs[ci] != 0);
        if (lane == 0) parbuf[ci][w] = m;
    }
    __syncthreads();

    if (tid == 0) {
        uint32_t* wp = ws + WS_PAR;
        #pragma unroll
        for (int ci = 0; ci < 2; ++ci) {
            int c = chunks[ci];
            unsigned long long m = parbuf[ci][0] ^ parbuf[ci][1]
                                 ^ parbuf[ci][2] ^ parbuf[ci][3];
            wp[(hb * 8 + c) * 2]     = (uint32_t)m;
            wp[(hb * 8 + c) * 2 + 1] = (uint32_t)(m >> 32);
        }
    }
}

// ---- Kernel C: majority vote over heads ----
__global__ __launch_bounds__(256) void softram_vote_kernel(
    const uint32_t* __restrict__ ws, float* __restrict__ out)
{
    int t = blockIdx.x * 256 + threadIdx.x;      // t = i*64 + b
    int b = t & 63;
    int i = t >> 6;
    const uint32_t* wp = ws + WS_PAR;
    int sum = 0;
    #pragma unroll
    for (int h = 0; h < 8; ++h) {
        int hb = h * 64 + b;
        uint32_t wv = wp[(hb * 8 + (i >> 6)) * 2 + ((i >> 5) & 1)];
        sum += (wv >> (i & 31)) & 1u;
    }
    out[t] = (sum > 4) ? 1.0f : 0.0f;            // THRESH = H/2 = 4
}

extern "C" void kernel_launch(void* const* d_in, const int* in_sizes, int n_in,
                              void* d_out, int out_size, void* d_ws, size_t ws_size,
                              hipStream_t stream) {
    const int*   tokens = (const int*)d_in[0];   // (512, 64)
    const int*   conn   = (const int*)d_in[1];   // (8, 64, 12)
    const float* ram    = (const float*)d_in[2]; // (8, 64, 4096)
    float*       out    = (float*)d_out;         // (512, 64)
    uint32_t*    ws     = (uint32_t*)d_ws;       // ~36 KB used

    softram_tok_kernel<<<32, 256, 0, stream>>>(tokens, ws);
    softram_parity_kernel<<<2048, 256, 0, stream>>>(conn, ram, ws);
    softram_vote_kernel<<<128, 256, 0, stream>>>(ws, out);
}